// Round 6
// baseline (264.660 us; speedup 1.0000x reference)
//
#include <hip/hip_runtime.h>
#include <cstdint>

#define DIMC 1024
#define NSEQ 2048
#define BATCH 2
#define HEADS 16
#define HD 64
#define MROWS (BATCH * NSEQ) /* 4096 */

typedef unsigned short u16;
typedef unsigned int u32;
typedef __attribute__((ext_vector_type(8))) short bf16x8;
typedef __attribute__((ext_vector_type(4))) float f32x4;

#if __has_builtin(__builtin_amdgcn_exp2f)
#define EXP2(x) __builtin_amdgcn_exp2f(x)
#else
#define EXP2(x) exp2f(x)
#endif

__device__ __forceinline__ u16 f2bf(float f) {
  union { float f; u32 u; } v; v.f = f;
  u32 u = v.u;
  return (u16)((u + 0x7fffu + ((u >> 16) & 1u)) >> 16);
}
__device__ __forceinline__ u32 pack_rne(float a, float b) {
  return (u32)f2bf(a) | ((u32)f2bf(b) << 16);
}
__device__ __forceinline__ u32 pack_trunc(float a, float b) {
  union { float f; u32 u; } x, y; x.f = a; y.f = b;
  return (x.u >> 16) | (y.u & 0xffff0000u);
}
// async global->LDS, 16B per lane. LDS dest must be wave-uniform base + lane*16.
__device__ __forceinline__ void gload_lds16(const void* g, void* l) {
  __builtin_amdgcn_global_load_lds((const __attribute__((address_space(1))) void*)g,
                                   (__attribute__((address_space(3))) void*)l, 16, 0, 0);
}

// ---------------- prep: LayerNorm+cast (blocks 0..12287) & W transpose+cast ----
__global__ __launch_bounds__(256)
void prep(const float* __restrict__ q, const float* __restrict__ k,
          const float* __restrict__ v,
          const float* __restrict__ gq, const float* __restrict__ bq,
          const float* __restrict__ gk, const float* __restrict__ bk,
          const float* __restrict__ gv, const float* __restrict__ bv,
          const float* __restrict__ w0, const float* __restrict__ w1,
          const float* __restrict__ w2, const float* __restrict__ w3,
          u16* __restrict__ xn, u16* __restrict__ wtout) {
  __shared__ float rs[4], rs2[4];
  __shared__ float tile[32][33];
  int tid = threadIdx.x;
  if (blockIdx.x < 3 * MROWS) {
    int rowid = blockIdx.x;
    int tensor = rowid >> 12;
    int r = rowid & 4095;
    const float *src, *g, *b;
    if (tensor == 0)      { src = q; g = gq; b = bq; }
    else if (tensor == 1) { src = k; g = gk; b = bk; }
    else                  { src = v; g = gv; b = bv; }
    src += (size_t)r * DIMC;
    u16* dst = xn + (size_t)tensor * MROWS * DIMC + (size_t)r * DIMC;
    float4 x = ((const float4*)src)[tid];
    float s  = x.x + x.y + x.z + x.w;
    float s2 = x.x*x.x + x.y*x.y + x.z*x.z + x.w*x.w;
    #pragma unroll
    for (int m = 1; m < 64; m <<= 1) { s += __shfl_xor(s, m); s2 += __shfl_xor(s2, m); }
    int wave = tid >> 6, lane = tid & 63;
    if (lane == 0) { rs[wave] = s; rs2[wave] = s2; }
    __syncthreads();
    s  = rs[0] + rs[1] + rs[2] + rs[3];
    s2 = rs2[0] + rs2[1] + rs2[2] + rs2[3];
    float mu  = s * (1.0f / DIMC);
    float var = s2 * (1.0f / DIMC) - mu * mu;
    float inv = rsqrtf(var + 1e-5f);
    float4 gg = ((const float4*)g)[tid];
    float4 bb = ((const float4*)b)[tid];
    uint2 o;
    o.x = pack_rne((x.x - mu) * inv * gg.x + bb.x, (x.y - mu) * inv * gg.y + bb.y);
    o.y = pack_rne((x.z - mu) * inv * gg.z + bb.z, (x.w - mu) * inv * gg.w + bb.w);
    ((uint2*)dst)[tid] = o;
  } else {
    int blk = blockIdx.x - 3 * MROWS;
    int widx = blk >> 10, t = blk & 1023;
    int ti = t >> 5, tj = t & 31;
    const float* W = (widx == 0) ? w0 : (widx == 1) ? w1 : (widx == 2) ? w2 : w3;
    u16* O = wtout + (size_t)widx * DIMC * DIMC;
    int tx = tid & 31, ty = tid >> 5;
    #pragma unroll
    for (int rr = 0; rr < 32; rr += 8)
      tile[ty + rr][tx] = W[(size_t)(ti * 32 + ty + rr) * DIMC + tj * 32 + tx];
    __syncthreads();
    #pragma unroll
    for (int rr = 0; rr < 32; rr += 8)
      O[(size_t)(tj * 32 + ty + rr) * DIMC + ti * 32 + tx] = f2bf(tile[tx][ty + rr]);
  }
}

// ---------------- fused QKV projection GEMM (grid.z selects Q/K/V) ----------------
// z==2 epilogue also produces V^T [bh][d][n] via LDS transpose (padded stride 136).
__global__ __launch_bounds__(256)
void qkv_gemm(const u16* __restrict__ xn, const u16* __restrict__ wt,
              const float* __restrict__ bq, const float* __restrict__ bk,
              const float* __restrict__ bv,
              float* __restrict__ out, u16* __restrict__ qh,
              u16* __restrict__ khb, u16* __restrict__ vtb) {
  __shared__ u16 smem[128 * 136];           // 34.8 KB; front 16 KB doubles as As/Bs
  u16* As = smem;                            // 128*32
  u16* Bs = smem + 4096;                     // 128*32
  u16* Ls = smem;                            // transpose tile [c][m] stride 136
  const int z = blockIdx.z;
  const u16* A  = xn + (size_t)z * MROWS * DIMC;
  const u16* Bt = wt + (size_t)z * DIMC * DIMC;
  const float* bias = (z == 0) ? bq : (z == 1) ? bk : bv;
  const int bm = blockIdx.x, bn = blockIdx.y;
  const int tid = threadIdx.x;
  const int wave = tid >> 6, lane = tid & 63;
  const int wm = (wave & 1) * 64, wn = (wave >> 1) * 64;
  const int row = lane & 15, quad = lane >> 4;
  const float QSCL = 0.18033688011112042f;  // 0.125 * log2(e)
  f32x4 acc[4][4] = {};
  for (int k0 = 0; k0 < DIMC; k0 += 32) {
    #pragma unroll
    for (int c = 0; c < 2; ++c) {
      int e = c * 2048 + tid * 8;
      int rr = e >> 5, col = e & 31;
      gload_lds16(&A[(size_t)(bm * 128 + rr) * DIMC + k0 + col], &As[e]);
      gload_lds16(&Bt[(size_t)(bn * 128 + rr) * DIMC + k0 + col], &Bs[e]);
    }
    __syncthreads();
    bf16x8 a[4], b[4];
    #pragma unroll
    for (int i = 0; i < 4; ++i)
      a[i] = *(const bf16x8*)(&As[(wm + i * 16 + row) * 32 + quad * 8]);
    #pragma unroll
    for (int j = 0; j < 4; ++j)
      b[j] = *(const bf16x8*)(&Bs[(wn + j * 16 + row) * 32 + quad * 8]);
    #pragma unroll
    for (int i = 0; i < 4; ++i)
      #pragma unroll
      for (int j = 0; j < 4; ++j)
        acc[i][j] = __builtin_amdgcn_mfma_f32_16x16x32_bf16(a[i], b[j], acc[i][j], 0, 0, 0);
    __syncthreads();
  }
  #pragma unroll
  for (int i = 0; i < 4; ++i) {
    #pragma unroll
    for (int j = 0; j < 4; ++j) {
      float val[4];
      #pragma unroll
      for (int r = 0; r < 4; ++r) {
        int m = bm * 128 + wm + i * 16 + quad * 4 + r;
        int c = bn * 128 + wn + j * 16 + row;
        val[r] = acc[i][j][r] + bias[c];
        int b_ = m >> 11, n = m & 2047, h = c >> 6, d = c & 63;
        int bh = b_ * HEADS + h;
        size_t hidx = ((size_t)bh * NSEQ + n) * HD + d;
        if (z == 0) {
          qh[hidx] = f2bf(val[r] * QSCL);   // pre-scaled for attention exp2
        } else {
          out[(size_t)z * MROWS * DIMC + hidx] = val[r];
          if (z == 1) khb[hidx] = f2bf(val[r]);
        }
      }
      if (z == 2) {
        int ct = wn + j * 16 + row;
        int mt = wm + i * 16 + quad * 4;
        u32* L = (u32*)(&Ls[ct * 136 + mt]);
        L[0] = pack_rne(val[0], val[1]);
        L[1] = pack_rne(val[2], val[3]);
      }
    }
  }
  if (z == 2) {
    __syncthreads();
    int b_ = (bm * 128) >> 11;
    int nbase = (bm * 128) & 2047;
    #pragma unroll
    for (int it = 0; it < 8; ++it) {
      int idx = it * 256 + tid;
      int ct = idx >> 4, ch = idx & 15;     // ct = c within tile, ch = 8-m chunk
      uint4 y = *(const uint4*)(&Ls[ct * 136 + ch * 8]);
      int c = bn * 128 + ct;
      int h = c >> 6, d = c & 63;
      size_t o = ((size_t)(b_ * HEADS + h) * HD + d) * NSEQ + nbase + ch * 8;
      *(uint4*)(&vtb[o]) = y;
    }
  }
}

// ---------------- output projection GEMM (64x128 tile, fp32 row-major out) ------
__global__ __launch_bounds__(256)
void out_gemm(const u16* __restrict__ A, const u16* __restrict__ Bt,
              const float* __restrict__ bias, float* __restrict__ outf) {
  __shared__ u16 As[64 * 32];
  __shared__ u16 Bs[128 * 32];
  const int bm = blockIdx.x, bn = blockIdx.y;
  const int tid = threadIdx.x;
  const int wave = tid >> 6, lane = tid & 63;
  const int wm = (wave & 1) * 32, wn = (wave >> 1) * 64;
  const int row = lane & 15, quad = lane >> 4;
  f32x4 acc[2][4] = {};
  for (int k0 = 0; k0 < DIMC; k0 += 32) {
    {
      int e = tid * 8;
      int rr = e >> 5, col = e & 31;
      gload_lds16(&A[(size_t)(bm * 64 + rr) * DIMC + k0 + col], &As[e]);
    }
    #pragma unroll
    for (int c = 0; c < 2; ++c) {
      int e = c * 2048 + tid * 8;
      int rr = e >> 5, col = e & 31;
      gload_lds16(&Bt[(size_t)(bn * 128 + rr) * DIMC + k0 + col], &Bs[e]);
    }
    __syncthreads();
    bf16x8 a[2], b[4];
    #pragma unroll
    for (int i = 0; i < 2; ++i)
      a[i] = *(const bf16x8*)(&As[(wm + i * 16 + row) * 32 + quad * 8]);
    #pragma unroll
    for (int j = 0; j < 4; ++j)
      b[j] = *(const bf16x8*)(&Bs[(wn + j * 16 + row) * 32 + quad * 8]);
    #pragma unroll
    for (int i = 0; i < 2; ++i)
      #pragma unroll
      for (int j = 0; j < 4; ++j)
        acc[i][j] = __builtin_amdgcn_mfma_f32_16x16x32_bf16(a[i], b[j], acc[i][j], 0, 0, 0);
    __syncthreads();
  }
  #pragma unroll
  for (int i = 0; i < 2; ++i)
    #pragma unroll
    for (int j = 0; j < 4; ++j)
      #pragma unroll
      for (int r = 0; r < 4; ++r) {
        int m = bm * 64 + wm + i * 16 + quad * 4 + r;
        int c = bn * 128 + wn + j * 16 + row;
        outf[(size_t)m * DIMC + c] = acc[i][j][r] + bias[c];
      }
}

// ---------------- fused flash attention (64-q blocks, batched 128-key tiles) ----
// grid (32 qtiles of 64, 32 bh), 4 waves; wave owns 16 q rows.
// r4 dataflow (full-tile S -> batched exp -> batched PV) at r5 occupancy:
// Ps 16x128/wave -> LDS 48KB -> 3 blocks/CU, grid 1024 -> 12 waves/CU.
__global__ __launch_bounds__(256)
void attn_fused(const u16* __restrict__ qh, const u16* __restrict__ kh,
                const u16* __restrict__ vt, u16* __restrict__ ao) {
  __shared__ u16 Ks[128 * 64];       // [key][d] chunk-swizzled
  __shared__ u16 Vs[64 * 128];       // [d][key] chunk-swizzled
  __shared__ u16 Ps[4][16 * 128];    // per wave [q][key] chunk-swizzled
  const int qtile = blockIdx.x;
  const int bh = blockIdx.y;
  const int b = bh >> 4, h = bh & 15;
  const int tid = threadIdx.x;
  const int wave = tid >> 6, lane = tid & 63;
  const int qi = lane & 15, quad = lane >> 4;
  const int sw = qi & 7;
  const size_t base = (size_t)bh * NSEQ * HD;
  bf16x8 qf[2];
  {
    int qrow = qtile * 64 + wave * 16 + qi;
    #pragma unroll
    for (int kc = 0; kc < 2; ++kc)
      qf[kc] = *(const bf16x8*)(&qh[base + (size_t)qrow * HD + kc * 32 + quad * 8]);
  }
  float li = 0.f;
  f32x4 oacc[4] = {};
  u16* myPs = &Ps[wave][0];
  for (int kt = 0; kt < NSEQ / 128; ++kt) {
    __syncthreads();
    #pragma unroll
    for (int c = 0; c < 4; ++c) {
      int p = c * 256 + tid;
      int rk = p >> 3, ck = p & 7;
      gload_lds16(&kh[base + (size_t)(kt * 128 + rk) * HD + (ck ^ (rk & 7)) * 8], &Ks[p * 8]);
      int rv = p >> 4, cv = p & 15;
      gload_lds16(&vt[base + (size_t)rv * NSEQ + kt * 128 + (cv ^ (rv & 15)) * 8], &Vs[p * 8]);
    }
    __syncthreads();
    // S^T[key][q] = K @ Q^T : 8 independent 2-MFMA chains
    f32x4 s[8];
    #pragma unroll
    for (int nt = 0; nt < 8; ++nt) {
      const u16* kr = &Ks[(nt * 16 + qi) * 64];
      f32x4 a = {};
      a = __builtin_amdgcn_mfma_f32_16x16x32_bf16(
          *(const bf16x8*)(&kr[(quad ^ sw) * 8]), qf[0], a, 0, 0, 0);
      a = __builtin_amdgcn_mfma_f32_16x16x32_bf16(
          *(const bf16x8*)(&kr[((4 + quad) ^ sw) * 8]), qf[1], a, 0, 0, 0);
      s[nt] = a;
    }
    // batched exp + pack into per-wave Ps (chunk XOR swizzle, 16 chunks)
    float psum = 0.f;
    u16* prow = &myPs[qi * 128];
    #pragma unroll
    for (int nt = 0; nt < 8; ++nt) {
      float p0 = EXP2(s[nt][0]);
      float p1 = EXP2(s[nt][1]);
      float p2 = EXP2(s[nt][2]);
      float p3 = EXP2(s[nt][3]);
      psum += (p0 + p1) + (p2 + p3);
      int chunk = (nt * 2 + (quad >> 1)) ^ qi;
      u32* w = (u32*)(&prow[chunk * 8 + (quad & 1) * 4]);
      w[0] = pack_trunc(p0, p1);
      w[1] = pack_trunc(p2, p3);
    }
    psum += __shfl_xor(psum, 16);
    psum += __shfl_xor(psum, 32);
    li += psum;
    asm volatile("" ::: "memory");  // order Ps writes before reads (same wave)
    // O^T[d][q] += V^T @ P : batched 16 MFMA
    #pragma unroll
    for (int kc = 0; kc < 4; ++kc) {
      int pc = ((kc * 4 + quad) ^ qi) * 8;
      bf16x8 pf = *(const bf16x8*)(&prow[pc]);
      #pragma unroll
      for (int dt = 0; dt < 4; ++dt) {
        bf16x8 vf = *(const bf16x8*)(&Vs[(dt * 16 + qi) * 128 + pc]);
        oacc[dt] = __builtin_amdgcn_mfma_f32_16x16x32_bf16(vf, pf, oacc[dt], 0, 0, 0);
      }
    }
  }
  {
    float inv = 1.0f / li;
    int token = b * NSEQ + qtile * 64 + wave * 16 + qi;
    #pragma unroll
    for (int dt = 0; dt < 4; ++dt) {
      int col = h * 64 + dt * 16 + quad * 4;
      *(u32*)(&ao[(size_t)token * DIMC + col])     = pack_rne(oacc[dt][0] * inv, oacc[dt][1] * inv);
      *(u32*)(&ao[(size_t)token * DIMC + col + 2]) = pack_rne(oacc[dt][2] * inv, oacc[dt][3] * inv);
    }
  }
}

extern "C" void kernel_launch(void* const* d_in, const int* in_sizes, int n_in,
                              void* d_out, int out_size, void* d_ws, size_t ws_size,
                              hipStream_t stream) {
  const float* q    = (const float*)d_in[0];
  const float* k    = (const float*)d_in[1];
  const float* v    = (const float*)d_in[2];
  const float* gq   = (const float*)d_in[3];
  const float* bqln = (const float*)d_in[4];
  const float* gk   = (const float*)d_in[5];
  const float* bkln = (const float*)d_in[6];
  const float* gv   = (const float*)d_in[7];
  const float* bvln = (const float*)d_in[8];
  const float* Wq   = (const float*)d_in[9];
  const float* bq   = (const float*)d_in[10];
  const float* Wk   = (const float*)d_in[11];
  const float* bk   = (const float*)d_in[12];
  const float* Wv   = (const float*)d_in[13];
  const float* bv   = (const float*)d_in[14];
  const float* Wp   = (const float*)d_in[15];
  const float* bp   = (const float*)d_in[16];
  float* out = (float*)d_out;

  char* ws = (char*)d_ws;
  u16* xn  = (u16*)(ws);                          // 3 x 4096x1024 bf16 (24MB)
  u16* wt  = (u16*)(ws + (size_t)25165824);       // 4 x 1024x1024 bf16 (8MB)
  u16* qh  = (u16*)(ws + (size_t)33554432);       // [bh][n][d] bf16 (pre-scaled)
  u16* khb = (u16*)(ws + (size_t)41943040);       // [bh][n][d] bf16
  u16* ao  = (u16*)(ws + (size_t)50331648);       // [token][1024] bf16
  // V^T lives in the output-0 region of d_out (16.78 MB, exactly fits);
  // out_gemm overwrites it afterwards.
  u16* vtb = (u16*)d_out;                         // [bh][d][n] bf16

  const size_t WEL = (size_t)DIMC * DIMC;

  prep<<<3 * MROWS + 4096, 256, 0, stream>>>(q, k, v, gq, bqln, gk, bkln, gv, bvln,
                                             Wq, Wk, Wv, Wp, xn, wt);
  qkv_gemm<<<dim3(MROWS / 128, DIMC / 128, 3), 256, 0, stream>>>(
      xn, wt, bq, bk, bv, out, qh, khb, vtb);
  attn_fused<<<dim3(NSEQ / 64, BATCH * HEADS), 256, 0, stream>>>(qh, khb, vtb, ao);
  out_gemm<<<dim3(MROWS / 64, DIMC / 128), 256, 0, stream>>>(ao, wt + 3 * WEL, bp, out);
}